// Round 9
// baseline (658.289 us; speedup 1.0000x reference)
//
#include <hip/hip_runtime.h>
#include <hip/hip_bf16.h>

#define NTOK 577
#define CH 768
#define NH 12
#define HD 64
#define M_ROWS 9232      // B * N
#define NPAD 592         // n pitch of E / Rsum
#define MPV 640          // m pitch of vT and E (5 * 128)
#define LDP 40           // padded LDS row pitch (f16) for GEMM tiles
#define P2P 136          // P2s LDS pitch (f16): 272 B = 17*16 -> b128-aligned
#define ESP 72           // qk_exp LDS E-tile pitch (f16): 144 B = 9*16 aligned

typedef _Float16 f16x8 __attribute__((ext_vector_type(8)));
typedef float f32x4 __attribute__((ext_vector_type(4)));

#define MFMA16(a, b, c) __builtin_amdgcn_mfma_f32_16x16x32_f16((a), (b), (c), 0, 0, 0)

__device__ __forceinline__ float bf2f(unsigned int u16) {
  union { unsigned int i; float f; } x; x.i = u16 << 16; return x.f;
}

__device__ __forceinline__ float ldin(const void* p, size_t i, bool f32) {
  return f32 ? ((const float*)p)[i]
             : __bfloat162float(((const __hip_bfloat16*)p)[i]);
}

__device__ __forceinline__ f16x8 ld8_cvt(const void* p, size_t idx, bool f32) {
  f16x8 r;
  if (f32) {
    const float* f = (const float*)p + idx;
    const float4 u = *(const float4*)f;
    const float4 v = *(const float4*)(f + 4);
    r[0]=(_Float16)u.x; r[1]=(_Float16)u.y; r[2]=(_Float16)u.z; r[3]=(_Float16)u.w;
    r[4]=(_Float16)v.x; r[5]=(_Float16)v.y; r[6]=(_Float16)v.z; r[7]=(_Float16)v.w;
  } else {
    const unsigned short* s = (const unsigned short*)p + idx;
    uint4 u = *(const uint4*)s;
    unsigned int w0=u.x, w1=u.y, w2=u.z, w3=u.w;
    r[0]=(_Float16)bf2f(w0&0xffffu); r[1]=(_Float16)bf2f(w0>>16);
    r[2]=(_Float16)bf2f(w1&0xffffu); r[3]=(_Float16)bf2f(w1>>16);
    r[4]=(_Float16)bf2f(w2&0xffffu); r[5]=(_Float16)bf2f(w2>>16);
    r[6]=(_Float16)bf2f(w3&0xffffu); r[7]=(_Float16)bf2f(w3>>16);
  }
  return r;
}

// ---- Kernel 0: detect input dtype (fp32 vs bf16).
__global__ void detect_dtype(const unsigned short* __restrict__ xs,
                             int* __restrict__ flag) {
  __shared__ int cnt;
  if (threadIdx.x == 0) cnt = 0;
  __syncthreads();
  int local = 0;
  for (int i = threadIdx.x; i < 4096; i += 256) {
    unsigned int u = xs[2 * i];
    unsigned int e = (u >> 7) & 0xFFu;
    if (e >= 140u) local++;
  }
  atomicAdd(&cnt, local);
  __syncthreads();
  if (threadIdx.x == 0) *flag = (cnt > 100) ? 1 : 0;
}

// ---- generic float zero-fill
__global__ void zero_f32(float* __restrict__ p, int n) {
  int i = blockIdx.x * 256 + threadIdx.x;
  if (i < n) p[i] = 0.f;
}

// ---- Kernel 1: qkv = x @ Wqkv^T via MFMA 16x16x32 f16, 128x128 tiles.
__global__ __launch_bounds__(256) void gemm_qkv_mfma(
    const void* __restrict__ X, const void* __restrict__ W,
    const int* __restrict__ flagp,
    _Float16* __restrict__ q, _Float16* __restrict__ k,
    _Float16* __restrict__ vT)
{
  const bool f32 = (*flagp != 0);
  __shared__ _Float16 As[128 * LDP];
  __shared__ _Float16 Bs[128 * LDP];
  const int tid = threadIdx.x;
  const int lane = tid & 63, wave = tid >> 6;
  const int quad = lane >> 4, l16 = lane & 15;
  const int wm = wave & 1, wo = wave >> 1;
  const int m0 = blockIdx.y * 128;
  const int bx = blockIdx.x;
  const int t = bx / 6;                    // 0=q 1=k 2=v
  const int o0 = bx * 128;
  const int o0loc = o0 - t * CH;

  const int srow = tid >> 2;
  const int scol = (tid & 3) * 8;
  const int arow0 = min(m0 + srow, M_ROWS - 1);
  const int arow1 = min(m0 + srow + 64, M_ROWS - 1);
  const int brow0 = o0 + srow;
  const int brow1 = o0 + srow + 64;

  f16x8 ra[2], rb[2];
  ra[0] = ld8_cvt(X, (size_t)arow0 * CH + scol, f32);
  ra[1] = ld8_cvt(X, (size_t)arow1 * CH + scol, f32);
  rb[0] = ld8_cvt(W, (size_t)brow0 * CH + scol, f32);
  rb[1] = ld8_cvt(W, (size_t)brow1 * CH + scol, f32);

  f32x4 acc[4][4] = {};
  for (int ks = 0; ks < CH / 32; ++ks) {
    __syncthreads();
    *(f16x8*)&As[(srow)      * LDP + scol] = ra[0];
    *(f16x8*)&As[(srow + 64) * LDP + scol] = ra[1];
    *(f16x8*)&Bs[(srow)      * LDP + scol] = rb[0];
    *(f16x8*)&Bs[(srow + 64) * LDP + scol] = rb[1];
    __syncthreads();
    if (ks + 1 < CH / 32) {
      int kc = (ks + 1) * 32 + scol;
      ra[0] = ld8_cvt(X, (size_t)arow0 * CH + kc, f32);
      ra[1] = ld8_cvt(X, (size_t)arow1 * CH + kc, f32);
      rb[0] = ld8_cvt(W, (size_t)brow0 * CH + kc, f32);
      rb[1] = ld8_cvt(W, (size_t)brow1 * CH + kc, f32);
    }
    f16x8 af[4], bf_[4];
    #pragma unroll
    for (int i = 0; i < 4; ++i)
      af[i] = *(const f16x8*)&As[(wm * 64 + i * 16 + l16) * LDP + quad * 8];
    #pragma unroll
    for (int j = 0; j < 4; ++j)
      bf_[j] = *(const f16x8*)&Bs[(wo * 64 + j * 16 + l16) * LDP + quad * 8];
    #pragma unroll
    for (int i = 0; i < 4; ++i)
      #pragma unroll
      for (int j = 0; j < 4; ++j)
        acc[i][j] = MFMA16(af[i], bf_[j], acc[i][j]);
  }

  #pragma unroll
  for (int i = 0; i < 4; ++i) {
    #pragma unroll
    for (int rr = 0; rr < 4; ++rr) {
      int m = m0 + wm * 64 + i * 16 + quad * 4 + rr;
      if (m >= M_ROWS) continue;
      int b = m / NTOK, n = m - b * NTOK;
      #pragma unroll
      for (int j = 0; j < 4; ++j) {
        int o = o0loc + wo * 64 + j * 16 + l16;
        int h = o >> 6, dd = o & 63;
        _Float16 val = (_Float16)acc[i][j][rr];
        if (t == 0)
          q[((size_t)(b * NH + h) * NTOK + n) * HD + dd] = val;
        else if (t == 1)
          k[((size_t)(b * NH + h) * NTOK + n) * HD + dd] = val;
        else
          vT[((size_t)(b * NH + h) * HD + dd) * MPV + n] = val;
      }
    }
  }
}

// ---- zero the m-pad of vT (m in [577,640)).
__global__ void zerofill_vt(_Float16* __restrict__ vT) {
  int idx = blockIdx.x * 256 + threadIdx.x;
  int r = idx >> 6, c = idx & 63;
  if (r < 16 * NH * HD && c < MPV - NTOK)
    vT[(size_t)r * MPV + NTOK + c] = (_Float16)0.f;
}

// ---- Kernel 2: QK^T + Wpre mix + exp -> E (unnormalized), partial rowsums.
// E tile staged in LDS, then written with full-128B-line f16x8 stores
// (round-8 scalar stores caused 4x HBM write amplification).
__global__ __launch_bounds__(256) void qk_exp(
    const _Float16* __restrict__ q, const _Float16* __restrict__ k,
    const void* __restrict__ Wpre, const int* __restrict__ flagp,
    _Float16* __restrict__ E, float* __restrict__ Rsum, int b0)
{
  const bool f32 = (*flagp != 0);
  __shared__ float wp[NH * NH];
  __shared__ _Float16 Es[NH * 16 * ESP];   // [g][n(16)][m(64)], pitch 72
  const int tid = threadIdx.x;
  if (tid < NH * NH) wp[tid] = ldin(Wpre, tid, f32) * 0.125f;  // fold scale
  __syncthreads();
  const int lane = tid & 63, wave = tid >> 6;
  const int quad = lane >> 4, l16 = lane & 15;
  const int bl = blockIdx.z, b = b0 + bl;
  const int n0 = blockIdx.y * 16;
  const int bx = blockIdx.x;
  const int m0 = bx * 64 + wave * 16;
  const int nq = min(n0 + l16, NTOK - 1);
  const int mk = min(m0 + l16, NTOK - 1);
  const size_t qbase = ((size_t)b * NH * NTOK + nq) * HD + quad * 8;
  const size_t kbase = ((size_t)b * NH * NTOK + mk) * HD + quad * 8;
  f32x4 acc[NH];
  #pragma unroll
  for (int h = 0; h < NH; ++h) {
    const size_t ho = (size_t)h * NTOK * HD;
    f16x8 a0 = *(const f16x8*)(q + qbase + ho);
    f16x8 bb0 = *(const f16x8*)(k + kbase + ho);
    f16x8 a1 = *(const f16x8*)(q + qbase + ho + 32);
    f16x8 bb1 = *(const f16x8*)(k + kbase + ho + 32);
    f32x4 z = {0.f, 0.f, 0.f, 0.f};
    z = MFMA16(a0, bb0, z);
    acc[h] = MFMA16(a1, bb1, z);
  }
  const int mloc = wave * 16 + l16;          // col within 64-wide tile
  const bool valid = (m0 + l16 < NTOK);
  #pragma unroll
  for (int g = 0; g < NH; ++g) {
    float e[4];
    float s0 = 0.f, s1 = 0.f, s2 = 0.f, s3 = 0.f;
    #pragma unroll
    for (int h = 0; h < NH; ++h) {
      float w = wp[g * NH + h];
      s0 += w * acc[h][0]; s1 += w * acc[h][1];
      s2 += w * acc[h][2]; s3 += w * acc[h][3];
    }
    e[0] = valid ? __expf(s0) : 0.f;
    e[1] = valid ? __expf(s1) : 0.f;
    e[2] = valid ? __expf(s2) : 0.f;
    e[3] = valid ? __expf(s3) : 0.f;
    #pragma unroll
    for (int r = 0; r < 4; ++r) {
      Es[(g * 16 + quad * 4 + r) * ESP + mloc] = (_Float16)e[r];
      float v = e[r];                       // reduce over the 16 m-columns
      v += __shfl_xor(v, 1); v += __shfl_xor(v, 2);
      v += __shfl_xor(v, 4); v += __shfl_xor(v, 8);
      e[r] = v;
    }
    if (l16 == 0) {
      #pragma unroll
      for (int r = 0; r < 4; ++r)
        atomicAdd(&Rsum[(size_t)(bl * NH + g) * NPAD + n0 + quad * 4 + r], e[r]);
    }
  }
  __syncthreads();
  // cooperative full-line store: 8 lanes x 16 B = 128 B contiguous per row
  const int sub = tid & 7;
  const int rb = tid >> 3;                   // 32 rows per pass
  #pragma unroll
  for (int it = 0; it < 6; ++it) {
    int idx = it * 32 + rb;                  // 0..191
    int g = idx >> 4, n = idx & 15;
    f16x8 vv = *(const f16x8*)&Es[(g * 16 + n) * ESP + sub * 8];
    *(f16x8*)&E[((size_t)(bl * NH + g) * NPAD + n0 + n) * MPV + bx * 64 + sub * 8] = vv;
  }
}

// ---- Kernel 3: read E, normalize + Wpost mix (packed f16), PV via MFMA.
__global__ __launch_bounds__(256) void pv_mix(
    const _Float16* __restrict__ E, const float* __restrict__ Rsum,
    const _Float16* __restrict__ vT, const void* __restrict__ Wpost,
    const int* __restrict__ flagp, _Float16* __restrict__ o1, int b0)
{
  const bool f32 = (*flagp != 0);
  __shared__ _Float16 P2s[NH][16][P2P];   // pitch 136 f16 = 272 B: b128-aligned
  __shared__ _Float16 w2s[NH * NH];
  __shared__ _Float16 rinvs[NH][16];
  const int tid = threadIdx.x;
  const int lane = tid & 63, w = tid >> 6;
  const int quad = lane >> 4, l16 = lane & 15;
  const int n0 = blockIdx.x * 16;
  const int bl = blockIdx.y, b = b0 + bl;
  if (tid < NH * NH) w2s[tid] = (_Float16)ldin(Wpost, tid, f32);
  if (tid < NH * 16) {
    int g = tid >> 4, n = tid & 15;
    float rv = Rsum[(size_t)(bl * NH + g) * NPAD + n0 + n];
    rinvs[g][n] = (_Float16)((n0 + n < NTOK && rv > 0.f) ? 1.f / rv : 0.f);
  }
  __syncthreads();
  _Float16 rloc[NH];
  #pragma unroll
  for (int h = 0; h < NH; ++h) rloc[h] = rinvs[h][l16];

  f32x4 O[3][4];
  #pragma unroll
  for (int j = 0; j < 3; ++j)
    #pragma unroll
    for (int dt = 0; dt < 4; ++dt) O[j][dt] = (f32x4){0.f, 0.f, 0.f, 0.f};
  const int gg0 = w * 3;

  for (int dmt = 0; dmt < 5; ++dmt) {
    const int mb = dmt * 128 + w * 32 + quad * 8;
    f16x8 ev[NH];
    #pragma unroll
    for (int h = 0; h < NH; ++h) {
      f16x8 t = *(const f16x8*)&E[((size_t)(bl * NH + h) * NPAD + n0 + l16) * MPV + mb];
      ev[h] = t * rloc[h];
    }
    __syncthreads();   // previous dmt's P2s readers done
    #pragma unroll
    for (int g = 0; g < NH; ++g) {
      f16x8 p = ev[0] * w2s[g * NH + 0];
      #pragma unroll
      for (int h = 1; h < NH; ++h) p += ev[h] * w2s[g * NH + h];
      *(f16x8*)&P2s[g][l16][w * 32 + quad * 8] = p;
    }
    __syncthreads();
    #pragma unroll
    for (int kc = 0; kc < 4; ++kc) {
      #pragma unroll
      for (int j = 0; j < 3; ++j) {
        const int g = gg0 + j;
        f16x8 a = *(const f16x8*)&P2s[g][l16][kc * 32 + quad * 8];
        #pragma unroll
        for (int dt = 0; dt < 4; ++dt) {
          f16x8 bv = *(const f16x8*)(
              vT + ((size_t)(b * NH + g) * HD + dt * 16 + l16) * MPV
                 + dmt * 128 + kc * 32 + quad * 8);
          O[j][dt] = MFMA16(a, bv, O[j][dt]);
        }
      }
    }
  }
  #pragma unroll
  for (int j = 0; j < 3; ++j)
    #pragma unroll
    for (int dt = 0; dt < 4; ++dt)
      #pragma unroll
      for (int r = 0; r < 4; ++r) {
        int n = n0 + quad * 4 + r;
        if (n < NTOK)
          o1[((size_t)b * NTOK + n) * CH + (gg0 + j) * HD + dt * 16 + l16] =
              (_Float16)O[j][dt][r];
      }
}

// ---- Kernel 4: out = o1 @ Wproj^T + bproj via MFMA, 128x128 tiles.
__global__ __launch_bounds__(256) void gemm_proj_mfma(
    const _Float16* __restrict__ A, const void* __restrict__ W,
    const void* __restrict__ bias, const int* __restrict__ flagp,
    void* __restrict__ out)
{
  const bool f32 = (*flagp != 0);
  __shared__ _Float16 As[128 * LDP];
  __shared__ _Float16 Bs[128 * LDP];
  const int tid = threadIdx.x;
  const int lane = tid & 63, wave = tid >> 6;
  const int quad = lane >> 4, l16 = lane & 15;
  const int wm = wave & 1, wo = wave >> 1;
  const int m0 = blockIdx.y * 128;
  const int o0 = blockIdx.x * 128;

  const int srow = tid >> 2;
  const int scol = (tid & 3) * 8;
  const int arow0 = min(m0 + srow, M_ROWS - 1);
  const int arow1 = min(m0 + srow + 64, M_ROWS - 1);
  const int brow0 = o0 + srow;
  const int brow1 = o0 + srow + 64;

  f16x8 ra[2], rb[2];
  ra[0] = *(const f16x8*)(A + (size_t)arow0 * CH + scol);
  ra[1] = *(const f16x8*)(A + (size_t)arow1 * CH + scol);
  rb[0] = ld8_cvt(W, (size_t)brow0 * CH + scol, f32);
  rb[1] = ld8_cvt(W, (size_t)brow1 * CH + scol, f32);

  f32x4 acc[4][4] = {};
  for (int ks = 0; ks < CH / 32; ++ks) {
    __syncthreads();
    *(f16x8*)&As[(srow)      * LDP + scol] = ra[0];
    *(f16x8*)&As[(srow + 64) * LDP + scol] = ra[1];
    *(f16x8*)&Bs[(srow)      * LDP + scol] = rb[0];
    *(f16x8*)&Bs[(srow + 64) * LDP + scol] = rb[1];
    __syncthreads();
    if (ks + 1 < CH / 32) {
      int kc = (ks + 1) * 32 + scol;
      ra[0] = *(const f16x8*)(A + (size_t)arow0 * CH + kc);
      ra[1] = *(const f16x8*)(A + (size_t)arow1 * CH + kc);
      rb[0] = ld8_cvt(W, (size_t)brow0 * CH + kc, f32);
      rb[1] = ld8_cvt(W, (size_t)brow1 * CH + kc, f32);
    }
    f16x8 af[4], bf_[4];
    #pragma unroll
    for (int i = 0; i < 4; ++i)
      af[i] = *(const f16x8*)&As[(wm * 64 + i * 16 + l16) * LDP + quad * 8];
    #pragma unroll
    for (int j = 0; j < 4; ++j)
      bf_[j] = *(const f16x8*)&Bs[(wo * 64 + j * 16 + l16) * LDP + quad * 8];
    #pragma unroll
    for (int i = 0; i < 4; ++i)
      #pragma unroll
      for (int j = 0; j < 4; ++j)
        acc[i][j] = MFMA16(af[i], bf_[j], acc[i][j]);
  }

  #pragma unroll
  for (int i = 0; i < 4; ++i) {
    #pragma unroll
    for (int rr = 0; rr < 4; ++rr) {
      int m = m0 + wm * 64 + i * 16 + quad * 4 + rr;
      if (m >= M_ROWS) continue;
      #pragma unroll
      for (int j = 0; j < 4; ++j) {
        int o = o0 + wo * 64 + j * 16 + l16;
        float val = acc[i][j][rr] + ldin(bias, o, f32);
        if (f32) ((float*)out)[(size_t)m * CH + o] = val;
        else ((__hip_bfloat16*)out)[(size_t)m * CH + o] = __float2bfloat16(val);
      }
    }
  }
}

extern "C" void kernel_launch(void* const* d_in, const int* in_sizes, int n_in,
                              void* d_out, int out_size, void* d_ws, size_t ws_size,
                              hipStream_t stream) {
  const void* x     = d_in[0];
  const void* Wqkv  = d_in[1];
  const void* Wproj = d_in[2];
  const void* bproj = d_in[3];
  const void* Wpre  = d_in[4];
  const void* Wpost = d_in[5];

  int* flag = (int*)d_ws;
  _Float16* ws = (_Float16*)((char*)d_ws + 16);
  const size_t QE  = (size_t)16 * NH * NTOK * HD;   // 7,090,176
  const size_t VTE = (size_t)16 * NH * HD * MPV;    // 7,864,320
  _Float16* q   = ws;
  _Float16* k   = q + QE;
  _Float16* vT  = k + QE;
  _Float16* o1  = vT + VTE;
  _Float16* E   = o1 + QE;

  // choose batch chunk for E/Rsum from available workspace
  const size_t fixedB = 16 + (3 * QE + VTE) * sizeof(_Float16);
  const size_t perE   = (size_t)NH * NPAD * MPV * sizeof(_Float16);  // 9,093,120
  const size_t perR   = (size_t)NH * NPAD * sizeof(float);           // 28,416
  int cb = 16;
  while (cb > 1 && fixedB + (size_t)cb * (perE + perR) > ws_size) cb >>= 1;
  float* Rsum = (float*)(E + (size_t)cb * NH * NPAD * MPV);
  const int rn = cb * NH * NPAD;

  dim3 blk(256);
  hipLaunchKernelGGL(detect_dtype, dim3(1), blk, 0, stream,
                     (const unsigned short*)x, flag);
  hipLaunchKernelGGL(gemm_qkv_mfma, dim3(18, 73), blk, 0, stream,
                     x, Wqkv, flag, q, k, vT);
  hipLaunchKernelGGL(zerofill_vt, dim3(16 * NH * HD * 64 / 256), blk, 0, stream, vT);
  for (int b0 = 0; b0 < 16; b0 += cb) {
    hipLaunchKernelGGL(zero_f32, dim3((rn + 255) / 256), blk, 0, stream, Rsum, rn);
    hipLaunchKernelGGL(qk_exp, dim3(10, 37, cb), blk, 0, stream,
                       q, k, Wpre, flag, E, Rsum, b0);
    hipLaunchKernelGGL(pv_mix, dim3(37, cb), blk, 0, stream,
                       E, Rsum, vT, Wpost, flag, o1, b0);
  }
  hipLaunchKernelGGL(gemm_proj_mfma, dim3(6, 73), blk, 0, stream,
                     o1, Wproj, bproj, flag, d_out);
}

// Round 10
// 594.154 us; speedup vs baseline: 1.1079x; 1.1079x over previous
//
#include <hip/hip_runtime.h>
#include <hip/hip_bf16.h>

#define NTOK 577
#define CH 768
#define NH 12
#define HD 64
#define M_ROWS 9232      // B * N
#define NPAD 592         // n pitch of E
#define MPV 640          // m pitch of vT and E (5 * 128)
#define LDP 40           // padded LDS row pitch (f16) for GEMM tiles
#define P2P 136          // P2s LDS pitch (f16): 272 B = 17*16 -> b128-aligned
#define ESP 72           // qk_exp LDS E-tile pitch (f16): 144 B = 9*16 aligned

typedef _Float16 f16x8 __attribute__((ext_vector_type(8)));
typedef float f32x4 __attribute__((ext_vector_type(4)));

#define MFMA16(a, b, c) __builtin_amdgcn_mfma_f32_16x16x32_f16((a), (b), (c), 0, 0, 0)

__device__ __forceinline__ float bf2f(unsigned int u16) {
  union { unsigned int i; float f; } x; x.i = u16 << 16; return x.f;
}

__device__ __forceinline__ float ldin(const void* p, size_t i, bool f32) {
  return f32 ? ((const float*)p)[i]
             : __bfloat162float(((const __hip_bfloat16*)p)[i]);
}

__device__ __forceinline__ f16x8 ld8_cvt(const void* p, size_t idx, bool f32) {
  f16x8 r;
  if (f32) {
    const float* f = (const float*)p + idx;
    const float4 u = *(const float4*)f;
    const float4 v = *(const float4*)(f + 4);
    r[0]=(_Float16)u.x; r[1]=(_Float16)u.y; r[2]=(_Float16)u.z; r[3]=(_Float16)u.w;
    r[4]=(_Float16)v.x; r[5]=(_Float16)v.y; r[6]=(_Float16)v.z; r[7]=(_Float16)v.w;
  } else {
    const unsigned short* s = (const unsigned short*)p + idx;
    uint4 u = *(const uint4*)s;
    unsigned int w0=u.x, w1=u.y, w2=u.z, w3=u.w;
    r[0]=(_Float16)bf2f(w0&0xffffu); r[1]=(_Float16)bf2f(w0>>16);
    r[2]=(_Float16)bf2f(w1&0xffffu); r[3]=(_Float16)bf2f(w1>>16);
    r[4]=(_Float16)bf2f(w2&0xffffu); r[5]=(_Float16)bf2f(w2>>16);
    r[6]=(_Float16)bf2f(w3&0xffffu); r[7]=(_Float16)bf2f(w3>>16);
  }
  return r;
}

// ---- Kernel 0: detect input dtype (fp32 vs bf16).
__global__ void detect_dtype(const unsigned short* __restrict__ xs,
                             int* __restrict__ flag) {
  __shared__ int cnt;
  if (threadIdx.x == 0) cnt = 0;
  __syncthreads();
  int local = 0;
  for (int i = threadIdx.x; i < 4096; i += 256) {
    unsigned int u = xs[2 * i];
    unsigned int e = (u >> 7) & 0xFFu;
    if (e >= 140u) local++;
  }
  atomicAdd(&cnt, local);
  __syncthreads();
  if (threadIdx.x == 0) *flag = (cnt > 100) ? 1 : 0;
}

// ---- Kernel 1: qkv = x @ Wqkv^T via MFMA 16x16x32 f16, 128x128 tiles.
__global__ __launch_bounds__(256) void gemm_qkv_mfma(
    const void* __restrict__ X, const void* __restrict__ W,
    const int* __restrict__ flagp,
    _Float16* __restrict__ q, _Float16* __restrict__ k,
    _Float16* __restrict__ vT)
{
  const bool f32 = (*flagp != 0);
  __shared__ _Float16 As[128 * LDP];
  __shared__ _Float16 Bs[128 * LDP];
  const int tid = threadIdx.x;
  const int lane = tid & 63, wave = tid >> 6;
  const int quad = lane >> 4, l16 = lane & 15;
  const int wm = wave & 1, wo = wave >> 1;
  const int m0 = blockIdx.y * 128;
  const int bx = blockIdx.x;
  const int t = bx / 6;                    // 0=q 1=k 2=v
  const int o0 = bx * 128;
  const int o0loc = o0 - t * CH;

  const int srow = tid >> 2;
  const int scol = (tid & 3) * 8;
  const int arow0 = min(m0 + srow, M_ROWS - 1);
  const int arow1 = min(m0 + srow + 64, M_ROWS - 1);
  const int brow0 = o0 + srow;
  const int brow1 = o0 + srow + 64;

  f16x8 ra[2], rb[2];
  ra[0] = ld8_cvt(X, (size_t)arow0 * CH + scol, f32);
  ra[1] = ld8_cvt(X, (size_t)arow1 * CH + scol, f32);
  rb[0] = ld8_cvt(W, (size_t)brow0 * CH + scol, f32);
  rb[1] = ld8_cvt(W, (size_t)brow1 * CH + scol, f32);

  f32x4 acc[4][4] = {};
  for (int ks = 0; ks < CH / 32; ++ks) {
    __syncthreads();
    *(f16x8*)&As[(srow)      * LDP + scol] = ra[0];
    *(f16x8*)&As[(srow + 64) * LDP + scol] = ra[1];
    *(f16x8*)&Bs[(srow)      * LDP + scol] = rb[0];
    *(f16x8*)&Bs[(srow + 64) * LDP + scol] = rb[1];
    __syncthreads();
    if (ks + 1 < CH / 32) {
      int kc = (ks + 1) * 32 + scol;
      ra[0] = ld8_cvt(X, (size_t)arow0 * CH + kc, f32);
      ra[1] = ld8_cvt(X, (size_t)arow1 * CH + kc, f32);
      rb[0] = ld8_cvt(W, (size_t)brow0 * CH + kc, f32);
      rb[1] = ld8_cvt(W, (size_t)brow1 * CH + kc, f32);
    }
    f16x8 af[4], bf_[4];
    #pragma unroll
    for (int i = 0; i < 4; ++i)
      af[i] = *(const f16x8*)&As[(wm * 64 + i * 16 + l16) * LDP + quad * 8];
    #pragma unroll
    for (int j = 0; j < 4; ++j)
      bf_[j] = *(const f16x8*)&Bs[(wo * 64 + j * 16 + l16) * LDP + quad * 8];
    #pragma unroll
    for (int i = 0; i < 4; ++i)
      #pragma unroll
      for (int j = 0; j < 4; ++j)
        acc[i][j] = MFMA16(af[i], bf_[j], acc[i][j]);
  }

  #pragma unroll
  for (int i = 0; i < 4; ++i) {
    #pragma unroll
    for (int rr = 0; rr < 4; ++rr) {
      int m = m0 + wm * 64 + i * 16 + quad * 4 + rr;
      if (m >= M_ROWS) continue;
      int b = m / NTOK, n = m - b * NTOK;
      #pragma unroll
      for (int j = 0; j < 4; ++j) {
        int o = o0loc + wo * 64 + j * 16 + l16;
        int h = o >> 6, dd = o & 63;
        _Float16 val = (_Float16)acc[i][j][rr];
        if (t == 0)
          q[((size_t)(b * NH + h) * NTOK + n) * HD + dd] = val;
        else if (t == 1)
          k[((size_t)(b * NH + h) * NTOK + n) * HD + dd] = val;
        else
          vT[((size_t)(b * NH + h) * HD + dd) * MPV + n] = val;
      }
    }
  }
}

// ---- zero the m-pad of vT (m in [577,640)).
__global__ void zerofill_vt(_Float16* __restrict__ vT) {
  int idx = blockIdx.x * 256 + threadIdx.x;
  int r = idx >> 6, c = idx & 63;
  if (r < 16 * NH * HD && c < MPV - NTOK)
    vT[(size_t)r * MPV + NTOK + c] = (_Float16)0.f;
}

// ---- Kernel 2: QK^T + Wpre mix + exp -> E (unnormalized).
// No rowsum atomics (round-9 postmortem: atomic line RMW doubled HBM write
// traffic and serialized the kernel). Row sums are recomputed in pv_mix.
__global__ __launch_bounds__(256) void qk_exp(
    const _Float16* __restrict__ q, const _Float16* __restrict__ k,
    const void* __restrict__ Wpre, const int* __restrict__ flagp,
    _Float16* __restrict__ E, int b0)
{
  const bool f32 = (*flagp != 0);
  __shared__ float wp[NH * NH];
  __shared__ _Float16 Es[NH * 16 * ESP];   // [g][n(16)][m(64)], pitch 72
  const int tid = threadIdx.x;
  if (tid < NH * NH) wp[tid] = ldin(Wpre, tid, f32) * 0.125f;  // fold scale
  __syncthreads();
  const int lane = tid & 63, wave = tid >> 6;
  const int quad = lane >> 4, l16 = lane & 15;
  const int bl = blockIdx.z, b = b0 + bl;
  const int n0 = blockIdx.y * 16;
  const int bx = blockIdx.x;
  const int m0 = bx * 64 + wave * 16;
  const int nq = min(n0 + l16, NTOK - 1);
  const int mk = min(m0 + l16, NTOK - 1);
  const size_t qbase = ((size_t)b * NH * NTOK + nq) * HD + quad * 8;
  const size_t kbase = ((size_t)b * NH * NTOK + mk) * HD + quad * 8;
  f32x4 acc[NH];
  #pragma unroll
  for (int h = 0; h < NH; ++h) {
    const size_t ho = (size_t)h * NTOK * HD;
    f16x8 a0 = *(const f16x8*)(q + qbase + ho);
    f16x8 bb0 = *(const f16x8*)(k + kbase + ho);
    f16x8 a1 = *(const f16x8*)(q + qbase + ho + 32);
    f16x8 bb1 = *(const f16x8*)(k + kbase + ho + 32);
    f32x4 z = {0.f, 0.f, 0.f, 0.f};
    z = MFMA16(a0, bb0, z);
    acc[h] = MFMA16(a1, bb1, z);
  }
  const int mloc = wave * 16 + l16;          // col within 64-wide tile
  const bool valid = (m0 + l16 < NTOK);
  #pragma unroll
  for (int g = 0; g < NH; ++g) {
    float s0 = 0.f, s1 = 0.f, s2 = 0.f, s3 = 0.f;
    #pragma unroll
    for (int h = 0; h < NH; ++h) {
      float w = wp[g * NH + h];
      s0 += w * acc[h][0]; s1 += w * acc[h][1];
      s2 += w * acc[h][2]; s3 += w * acc[h][3];
    }
    Es[(g * 16 + quad * 4 + 0) * ESP + mloc] = (_Float16)(valid ? __expf(s0) : 0.f);
    Es[(g * 16 + quad * 4 + 1) * ESP + mloc] = (_Float16)(valid ? __expf(s1) : 0.f);
    Es[(g * 16 + quad * 4 + 2) * ESP + mloc] = (_Float16)(valid ? __expf(s2) : 0.f);
    Es[(g * 16 + quad * 4 + 3) * ESP + mloc] = (_Float16)(valid ? __expf(s3) : 0.f);
  }
  __syncthreads();
  // cooperative full-line store: 8 lanes x 16 B = 128 B contiguous per row
  const int sub = tid & 7;
  const int rbk = tid >> 3;                  // 32 rows per pass
  #pragma unroll
  for (int it = 0; it < 6; ++it) {
    int idx = it * 32 + rbk;                 // 0..191
    int g = idx >> 4, n = idx & 15;
    f16x8 vv = *(const f16x8*)&Es[(g * 16 + n) * ESP + sub * 8];
    *(f16x8*)&E[((size_t)(bl * NH + g) * NPAD + n0 + n) * MPV + bx * 64 + sub * 8] = vv;
  }
}

// ---- Kernel 3: read E, compute row sums (phase A), normalize + Wpost mix
// (packed f16), PV via MFMA (phase B).
__global__ __launch_bounds__(256) void pv_mix(
    const _Float16* __restrict__ E, const _Float16* __restrict__ vT,
    const void* __restrict__ Wpost, const int* __restrict__ flagp,
    _Float16* __restrict__ o1, int b0)
{
  const bool f32 = (*flagp != 0);
  __shared__ _Float16 P2s[NH][16][P2P];   // pitch 136 f16 = 272 B: b128-aligned
  __shared__ _Float16 w2s[NH * NH];
  __shared__ float wsum[4][NH][16];
  __shared__ _Float16 rinvs[NH][16];
  const int tid = threadIdx.x;
  const int lane = tid & 63, w = tid >> 6;
  const int quad = lane >> 4, l16 = lane & 15;
  const int n0 = blockIdx.x * 16;
  const int bl = blockIdx.y, b = b0 + bl;
  if (tid < NH * NH) w2s[tid] = (_Float16)ldin(Wpost, tid, f32);

  // ---- phase A: row sums of E (replaces round-9's atomic Rsum)
  float s[NH];
  #pragma unroll
  for (int h = 0; h < NH; ++h) s[h] = 0.f;
  for (int dmt = 0; dmt < 5; ++dmt) {
    const int mb = dmt * 128 + w * 32 + quad * 8;
    #pragma unroll
    for (int h = 0; h < NH; ++h) {
      f16x8 t = *(const f16x8*)&E[((size_t)(bl * NH + h) * NPAD + n0 + l16) * MPV + mb];
      #pragma unroll
      for (int j = 0; j < 8; ++j) s[h] += (float)t[j];
    }
  }
  #pragma unroll
  for (int h = 0; h < NH; ++h) {
    s[h] += __shfl_xor(s[h], 16);
    s[h] += __shfl_xor(s[h], 32);
  }
  if (quad == 0) {
    #pragma unroll
    for (int h = 0; h < NH; ++h) wsum[w][h][l16] = s[h];
  }
  __syncthreads();
  if (tid < NH * 16) {
    int g = tid >> 4, n = tid & 15;
    float tot = wsum[0][g][n] + wsum[1][g][n] + wsum[2][g][n] + wsum[3][g][n];
    rinvs[g][n] = (_Float16)(tot > 0.f ? 1.f / tot : 0.f);
  }
  __syncthreads();
  _Float16 rloc[NH];
  #pragma unroll
  for (int h = 0; h < NH; ++h) rloc[h] = rinvs[h][l16];

  // ---- phase B: normalize + Wpost mix + PV
  f32x4 O[3][4];
  #pragma unroll
  for (int j = 0; j < 3; ++j)
    #pragma unroll
    for (int dt = 0; dt < 4; ++dt) O[j][dt] = (f32x4){0.f, 0.f, 0.f, 0.f};
  const int gg0 = w * 3;

  for (int dmt = 0; dmt < 5; ++dmt) {
    const int mb = dmt * 128 + w * 32 + quad * 8;
    f16x8 ev[NH];
    #pragma unroll
    for (int h = 0; h < NH; ++h) {
      f16x8 t = *(const f16x8*)&E[((size_t)(bl * NH + h) * NPAD + n0 + l16) * MPV + mb];
      ev[h] = t * rloc[h];
    }
    __syncthreads();   // previous dmt's P2s readers done
    #pragma unroll
    for (int g = 0; g < NH; ++g) {
      f16x8 p = ev[0] * w2s[g * NH + 0];
      #pragma unroll
      for (int h = 1; h < NH; ++h) p += ev[h] * w2s[g * NH + h];
      *(f16x8*)&P2s[g][l16][w * 32 + quad * 8] = p;
    }
    __syncthreads();
    #pragma unroll
    for (int kc = 0; kc < 4; ++kc) {
      #pragma unroll
      for (int j = 0; j < 3; ++j) {
        const int g = gg0 + j;
        f16x8 a = *(const f16x8*)&P2s[g][l16][kc * 32 + quad * 8];
        #pragma unroll
        for (int dt = 0; dt < 4; ++dt) {
          f16x8 bv = *(const f16x8*)(
              vT + ((size_t)(b * NH + g) * HD + dt * 16 + l16) * MPV
                 + dmt * 128 + kc * 32 + quad * 8);
          O[j][dt] = MFMA16(a, bv, O[j][dt]);
        }
      }
    }
  }
  #pragma unroll
  for (int j = 0; j < 3; ++j)
    #pragma unroll
    for (int dt = 0; dt < 4; ++dt)
      #pragma unroll
      for (int r = 0; r < 4; ++r) {
        int n = n0 + quad * 4 + r;
        if (n < NTOK)
          o1[((size_t)b * NTOK + n) * CH + (gg0 + j) * HD + dt * 16 + l16] =
              (_Float16)O[j][dt][r];
      }
}

// ---- Kernel 4: out = o1 @ Wproj^T + bproj via MFMA, 128x128 tiles.
__global__ __launch_bounds__(256) void gemm_proj_mfma(
    const _Float16* __restrict__ A, const void* __restrict__ W,
    const void* __restrict__ bias, const int* __restrict__ flagp,
    void* __restrict__ out)
{
  const bool f32 = (*flagp != 0);
  __shared__ _Float16 As[128 * LDP];
  __shared__ _Float16 Bs[128 * LDP];
  const int tid = threadIdx.x;
  const int lane = tid & 63, wave = tid >> 6;
  const int quad = lane >> 4, l16 = lane & 15;
  const int wm = wave & 1, wo = wave >> 1;
  const int m0 = blockIdx.y * 128;
  const int o0 = blockIdx.x * 128;

  const int srow = tid >> 2;
  const int scol = (tid & 3) * 8;
  const int arow0 = min(m0 + srow, M_ROWS - 1);
  const int arow1 = min(m0 + srow + 64, M_ROWS - 1);
  const int brow0 = o0 + srow;
  const int brow1 = o0 + srow + 64;

  f16x8 ra[2], rb[2];
  ra[0] = *(const f16x8*)(A + (size_t)arow0 * CH + scol);
  ra[1] = *(const f16x8*)(A + (size_t)arow1 * CH + scol);
  rb[0] = ld8_cvt(W, (size_t)brow0 * CH + scol, f32);
  rb[1] = ld8_cvt(W, (size_t)brow1 * CH + scol, f32);

  f32x4 acc[4][4] = {};
  for (int ks = 0; ks < CH / 32; ++ks) {
    __syncthreads();
    *(f16x8*)&As[(srow)      * LDP + scol] = ra[0];
    *(f16x8*)&As[(srow + 64) * LDP + scol] = ra[1];
    *(f16x8*)&Bs[(srow)      * LDP + scol] = rb[0];
    *(f16x8*)&Bs[(srow + 64) * LDP + scol] = rb[1];
    __syncthreads();
    if (ks + 1 < CH / 32) {
      int kc = (ks + 1) * 32 + scol;
      ra[0] = *(const f16x8*)(A + (size_t)arow0 * CH + kc);
      ra[1] = *(const f16x8*)(A + (size_t)arow1 * CH + kc);
      rb[0] = ld8_cvt(W, (size_t)brow0 * CH + kc, f32);
      rb[1] = ld8_cvt(W, (size_t)brow1 * CH + kc, f32);
    }
    f16x8 af[4], bf_[4];
    #pragma unroll
    for (int i = 0; i < 4; ++i)
      af[i] = *(const f16x8*)&As[(wm * 64 + i * 16 + l16) * LDP + quad * 8];
    #pragma unroll
    for (int j = 0; j < 4; ++j)
      bf_[j] = *(const f16x8*)&Bs[(wo * 64 + j * 16 + l16) * LDP + quad * 8];
    #pragma unroll
    for (int i = 0; i < 4; ++i)
      #pragma unroll
      for (int j = 0; j < 4; ++j)
        acc[i][j] = MFMA16(af[i], bf_[j], acc[i][j]);
  }

  #pragma unroll
  for (int i = 0; i < 4; ++i) {
    #pragma unroll
    for (int rr = 0; rr < 4; ++rr) {
      int m = m0 + wm * 64 + i * 16 + quad * 4 + rr;
      if (m >= M_ROWS) continue;
      #pragma unroll
      for (int j = 0; j < 4; ++j) {
        int o = o0 + wo * 64 + j * 16 + l16;
        float val = acc[i][j][rr] + ldin(bias, o, f32);
        if (f32) ((float*)out)[(size_t)m * CH + o] = val;
        else ((__hip_bfloat16*)out)[(size_t)m * CH + o] = __float2bfloat16(val);
      }
    }
  }
}

extern "C" void kernel_launch(void* const* d_in, const int* in_sizes, int n_in,
                              void* d_out, int out_size, void* d_ws, size_t ws_size,
                              hipStream_t stream) {
  const void* x     = d_in[0];
  const void* Wqkv  = d_in[1];
  const void* Wproj = d_in[2];
  const void* bproj = d_in[3];
  const void* Wpre  = d_in[4];
  const void* Wpost = d_in[5];

  int* flag = (int*)d_ws;
  _Float16* ws = (_Float16*)((char*)d_ws + 16);
  const size_t QE  = (size_t)16 * NH * NTOK * HD;   // 7,090,176
  const size_t VTE = (size_t)16 * NH * HD * MPV;    // 7,864,320
  _Float16* q   = ws;
  _Float16* k   = q + QE;
  _Float16* vT  = k + QE;
  _Float16* o1  = vT + VTE;
  _Float16* E   = o1 + QE;

  // choose batch chunk for E from available workspace
  const size_t fixedB = 16 + (3 * QE + VTE) * sizeof(_Float16);
  const size_t perE   = (size_t)NH * NPAD * MPV * sizeof(_Float16);  // 9,093,120
  int cb = 16;
  while (cb > 1 && fixedB + (size_t)cb * perE > ws_size) cb >>= 1;

  dim3 blk(256);
  hipLaunchKernelGGL(detect_dtype, dim3(1), blk, 0, stream,
                     (const unsigned short*)x, flag);
  hipLaunchKernelGGL(gemm_qkv_mfma, dim3(18, 73), blk, 0, stream,
                     x, Wqkv, flag, q, k, vT);
  hipLaunchKernelGGL(zerofill_vt, dim3(16 * NH * HD * 64 / 256), blk, 0, stream, vT);
  for (int b0 = 0; b0 < 16; b0 += cb) {
    hipLaunchKernelGGL(qk_exp, dim3(10, 37, cb), blk, 0, stream,
                       q, k, Wpre, flag, E, b0);
    hipLaunchKernelGGL(pv_mix, dim3(37, cb), blk, 0, stream,
                       E, vT, Wpost, flag, o1, b0);
  }
  hipLaunchKernelGGL(gemm_proj_mfma, dim3(6, 73), blk, 0, stream,
                     o1, Wproj, bproj, flag, d_out);
}